// Round 3
// baseline (112.725 us; speedup 1.0000x reference)
//
#include <hip/hip_runtime.h>
#include <hip/hip_bf16.h>

#define ALPHA  0.2f
#define L2E    1.4426950408889634f

typedef __attribute__((ext_vector_type(8))) short  short8;
typedef __attribute__((ext_vector_type(4))) float  f32x4;
typedef unsigned short u16;

__device__ __forceinline__ u16 f2bf(float f) {
    union { float f; unsigned int u; } v; v.f = f;
    unsigned int r = (v.u + 0x7FFFu + ((v.u >> 16) & 1u)) >> 16;   // RNE
    return (u16)r;
}
__device__ __forceinline__ float lrelu(float x) { return fmaxf(x, ALPHA * x); }

// ---------------- prep: W -> wbt (bf16, [c][k]); w1 = W@a1, w2 = W@a2 ------
__global__ void prep(const float* __restrict__ W, const float* __restrict__ a1,
                     const float* __restrict__ a2, u16* __restrict__ wbt,
                     float* __restrict__ w1, float* __restrict__ w2) {
    int b = blockIdx.x;
    if (b < 64) {
        int t  = threadIdx.x;
        int kk = t >> 6;
        int c4 = (t & 63) * 4;
        int k  = b * 4 + kk;
        float4 w = *(const float4*)(W + (size_t)k * 256 + c4);
        wbt[(c4 + 0) * 256 + k] = f2bf(w.x);
        wbt[(c4 + 1) * 256 + k] = f2bf(w.y);
        wbt[(c4 + 2) * 256 + k] = f2bf(w.z);
        wbt[(c4 + 3) * 256 + k] = f2bf(w.w);
    } else {
        int bb = b - 64;                       // 0..3
        int wv = threadIdx.x >> 6, lane = threadIdx.x & 63;
        for (int kk = 0; kk < 16; ++kk) {
            int k = bb * 64 + wv * 16 + kk;
            float4 wv4 = *(const float4*)(W + (size_t)k * 256 + 4 * lane);
            float4 a14 = *(const float4*)(a1 + 4 * lane);
            float4 a24 = *(const float4*)(a2 + 4 * lane);
            float d1 = wv4.x*a14.x + wv4.y*a14.y + wv4.z*a14.z + wv4.w*a14.w;
            float d2 = wv4.x*a24.x + wv4.y*a24.y + wv4.z*a24.z + wv4.w*a24.w;
            #pragma unroll
            for (int off = 32; off; off >>= 1) {
                d1 += __shfl_xor(d1, off);
                d2 += __shfl_xor(d2, off);
            }
            if (lane == 0) { w1[k] = d1; w2[k] = d2; }
        }
    }
}

// ======================= Kernel A: gather+LN+s1/s2+GEMM1 ====================
// grid 512: block = (b, ihalf). LDS 64KB -> 2 blocks/CU.
// xa tile [128 r][256 k] bf16, 512B rows, 16B slot swizzle: slot = (k>>3)^(r&7)
// then reused as hT tile [256 c][128 i] bf16, 256B rows, slot = (i>>3)^(c&7)
__global__ __launch_bounds__(256, 2)
void kA(const int* __restrict__ item_seq, const float* __restrict__ emb,
        const float* __restrict__ pos, const float* __restrict__ gamma,
        const float* __restrict__ beta, const u16* __restrict__ wbt,
        const float* __restrict__ w1, const float* __restrict__ w2,
        float* __restrict__ s1g, float* __restrict__ s2g, u16* __restrict__ htg)
{
    __shared__ u16 xa[128 * 256];   // 64 KB
    const int bid = blockIdx.x;
    const int b   = bid >> 1, ih = bid & 1;
    const int tid = threadIdx.x;
    const int lane = tid & 63, wv = tid >> 6, g = lane >> 4, li = lane & 15;

    // ---- Phase A: gather + LN + fused s1/s2 dots (thread = half row) ------
    {
        int rl = tid >> 1, hs = tid & 1;
        int r  = ih * 128 + rl;
        int iw = item_seq[(size_t)b * 256 + r];
        const float4* ep = (const float4*)(emb + (size_t)iw * 256 + hs * 128);
        const float4* pp = (const float4*)(pos + (size_t)r  * 256 + hs * 128);
        float4 xr[32];
        float s = 0.f, q = 0.f;
        #pragma unroll
        for (int m = 0; m < 32; ++m) {
            float4 e = ep[m], p = pp[m];
            float4 v; v.x = e.x + p.x; v.y = e.y + p.y; v.z = e.z + p.z; v.w = e.w + p.w;
            xr[m] = v;
            s += v.x + v.y + v.z + v.w;
            q += v.x*v.x + v.y*v.y + v.z*v.z + v.w*v.w;
        }
        s += __shfl_xor(s, 1);  q += __shfl_xor(q, 1);
        float mu  = s * (1.0f / 256.0f);
        float var = q * (1.0f / 256.0f) - mu * mu;
        float rs  = rsqrtf(var + 1e-12f);
        const float4* gp  = (const float4*)(gamma + hs * 128);
        const float4* bp  = (const float4*)(beta  + hs * 128);
        const float4* w1p = (const float4*)(w1 + hs * 128);
        const float4* w2p = (const float4*)(w2 + hs * 128);
        float d1 = 0.f, d2 = 0.f;
        #pragma unroll
        for (int mp = 0; mp < 16; ++mp) {
            float4 va = xr[2*mp], vb = xr[2*mp+1];
            float4 ga = gp[2*mp], gb = gp[2*mp+1];
            float4 ba = bp[2*mp], bb = bp[2*mp+1];
            float4 ua = w1p[2*mp], ub = w1p[2*mp+1];
            float4 ta = w2p[2*mp], tb = w2p[2*mp+1];
            float y0 = (va.x - mu) * rs * ga.x + ba.x;
            float y1 = (va.y - mu) * rs * ga.y + ba.y;
            float y2 = (va.z - mu) * rs * ga.z + ba.z;
            float y3 = (va.w - mu) * rs * ga.w + ba.w;
            float y4 = (vb.x - mu) * rs * gb.x + bb.x;
            float y5 = (vb.y - mu) * rs * gb.y + bb.y;
            float y6 = (vb.z - mu) * rs * gb.z + bb.z;
            float y7 = (vb.w - mu) * rs * gb.w + bb.w;
            d1 += y0*ua.x + y1*ua.y + y2*ua.z + y3*ua.w + y4*ub.x + y5*ub.y + y6*ub.z + y7*ub.w;
            d2 += y0*ta.x + y1*ta.y + y2*ta.z + y3*ta.w + y4*tb.x + y5*tb.y + y6*tb.z + y7*tb.w;
            union { u16 us[8]; short8 v8; } pk;
            pk.us[0] = f2bf(y0); pk.us[1] = f2bf(y1); pk.us[2] = f2bf(y2); pk.us[3] = f2bf(y3);
            pk.us[4] = f2bf(y4); pk.us[5] = f2bf(y5); pk.us[6] = f2bf(y6); pk.us[7] = f2bf(y7);
            int ch = hs * 16 + mp;
            *(short8*)&xa[rl * 256 + ((ch ^ (rl & 7)) << 3)] = pk.v8;
        }
        d1 += __shfl_xor(d1, 1);  d2 += __shfl_xor(d2, 1);
        if (hs == 0) s1g[b * 256 + r] = d1;
        else         s2g[b * 256 + r] = d2;
    }
    __syncthreads();

    // ---- GEMM1: h[128x256] = xa @ Wb ; B-frags direct from global (L2) ----
    const int im = wv >> 1;    // i 64-range
    const int ng = wv & 1;     // c 128-range
    f32x4 acc[4][8];
    #pragma unroll
    for (int mt = 0; mt < 4; ++mt)
        #pragma unroll
        for (int nt = 0; nt < 8; ++nt)
            acc[mt][nt] = (f32x4){0.f, 0.f, 0.f, 0.f};

    #pragma unroll
    for (int ks = 0; ks < 8; ++ks) {
        short8 bfr[8];
        #pragma unroll
        for (int nt = 0; nt < 8; ++nt) {
            int c = ng * 128 + nt * 16 + li;
            bfr[nt] = *(const short8*)(wbt + (size_t)c * 256 + ks * 32 + g * 8);
        }
        #pragma unroll
        for (int mt = 0; mt < 4; ++mt) {
            int rl = im * 64 + mt * 16 + li;
            int kc = ks * 4 + g;
            short8 af = *(const short8*)&xa[rl * 256 + ((kc ^ (rl & 7)) << 3)];
            #pragma unroll
            for (int nt = 0; nt < 8; ++nt)
                acc[mt][nt] = __builtin_amdgcn_mfma_f32_16x16x32_bf16(
                    af, bfr[nt], acc[mt][nt], 0, 0, 0);
        }
    }
    __syncthreads();   // xa reads done; safe to overwrite with hT

    // ---- transpose: hT tile [c 256][i 128], 256B rows ----------------------
    #pragma unroll
    for (int mt = 0; mt < 4; ++mt)
        #pragma unroll
        for (int nt = 0; nt < 8; ++nt) {
            int c  = ng * 128 + nt * 16 + li;
            int il = im * 64 + mt * 16 + 4 * g;
            uint2 v;
            v.x = (unsigned)f2bf(acc[mt][nt][0]) | ((unsigned)f2bf(acc[mt][nt][1]) << 16);
            v.y = (unsigned)f2bf(acc[mt][nt][2]) | ((unsigned)f2bf(acc[mt][nt][3]) << 16);
            *(uint2*)&xa[c * 128 + (((il >> 3) ^ (c & 7)) << 3) + (il & 7)] = v;
        }
    __syncthreads();

    // ---- coalesced store: thread = c row (256B), pre-swizzled global layout
    {
        const uint4* sp = (const uint4*)&xa[(size_t)tid * 128];
        uint4* dp = (uint4*)(htg + ((size_t)(b * 256 + tid)) * 256 + ih * 128);
        #pragma unroll
        for (int it = 0; it < 16; ++it) dp[it] = sp[it];
    }
}

// ======================= Kernel B: softmax + PV =============================
// grid 512: block = (b, chalf). LDS ~69KB -> 2 blocks/CU.
__global__ __launch_bounds__(256, 2)
void kB(const float* __restrict__ s1g, const float* __restrict__ s2g,
        const u16* __restrict__ htg, float* __restrict__ out)
{
    __shared__ u16   ht[128 * 256];          // 64 KB, [c-local][j-slots] 512B rows
    __shared__ float s2s[256], s1S[256], mS[256], lS[256];
    __shared__ float red[4];
    const int bid = blockIdx.x;
    const int b   = bid >> 1, ch = bid & 1;
    const int tid = threadIdx.x;
    const int lane = tid & 63, wv = tid >> 6, g = lane >> 4, li = lane & 15;

    // stats inputs first (so barrier #1 is cheap)
    float s1v = s1g[b * 256 + tid];
    float s2v = s2g[b * 256 + tid];
    s2s[tid] = s2v; s1S[tid] = s1v;
    float m = s2v;
    #pragma unroll
    for (int off = 32; off; off >>= 1) m = fmaxf(m, __shfl_xor(m, off));
    if (lane == 0) red[wv] = m;
    __syncthreads();

    // issue hT staging (16 x 4KB rounds); latency hides under stats below
    {
        const u16* sb = htg + ((size_t)(b * 256 + ch * 128)) * 256;
        #pragma unroll
        for (int it = 0; it < 16; ++it) {
            const u16* src = sb + it * 2048 + wv * 512 + lane * 8;
            u16* dst = &ht[it * 2048 + wv * 512];
            __builtin_amdgcn_global_load_lds(
                (const __attribute__((address_space(1))) void*)src,
                (__attribute__((address_space(3))) void*)dst, 16, 0, 0);
        }
    }

    // softmax stats: exact row max via separable trick, then denom
    {
        float s2max = fmaxf(fmaxf(red[0], red[1]), fmaxf(red[2], red[3]));
        float mi  = lrelu(s1v + s2max);
        float sum = 0.f;
        #pragma unroll 4
        for (int j = 0; j < 256; ++j) {
            float e = lrelu(s1v + s2s[j]);
            sum += __builtin_amdgcn_exp2f((e - mi) * L2E);
        }
        mS[tid] = mi; lS[tid] = 1.0f / sum;
    }
    __syncthreads();   // drains staging vmcnt + publishes mS/lS

    // ---- PV: out[i 256][c 128] = P @ h ------------------------------------
    f32x4 oacc[4][8];
    #pragma unroll
    for (int mt = 0; mt < 4; ++mt)
        #pragma unroll
        for (int nt = 0; nt < 8; ++nt)
            oacc[mt][nt] = (f32x4){0.f, 0.f, 0.f, 0.f};

    float s1r[4], mv[4], lv[4];
    #pragma unroll
    for (int mt = 0; mt < 4; ++mt) {
        int i = wv * 64 + mt * 16 + li;
        s1r[mt] = s1S[i]; mv[mt] = mS[i]; lv[mt] = lS[i];
    }

    #pragma unroll
    for (int js = 0; js < 8; ++js) {
        float s2l[8];
        #pragma unroll
        for (int jj = 0; jj < 8; ++jj) s2l[jj] = s2s[js * 32 + g * 8 + jj];

        short8 pfr[4];
        #pragma unroll
        for (int mt = 0; mt < 4; ++mt) {
            union { unsigned int u[4]; short8 s; } pk;
            #pragma unroll
            for (int q2 = 0; q2 < 4; ++q2) {
                float e0 = lrelu(s1r[mt] + s2l[2 * q2]);
                float e1 = lrelu(s1r[mt] + s2l[2 * q2 + 1]);
                float p0 = __builtin_amdgcn_exp2f((e0 - mv[mt]) * L2E) * lv[mt];
                float p1 = __builtin_amdgcn_exp2f((e1 - mv[mt]) * L2E) * lv[mt];
                pk.u[q2] = (unsigned int)f2bf(p0) | ((unsigned int)f2bf(p1) << 16);
            }
            pfr[mt] = pk.s;
        }
        #pragma unroll
        for (int nt = 0; nt < 8; ++nt) {
            int cl = nt * 16 + li;
            short8 vf = *(const short8*)&ht[cl * 256 + (((js * 4 + g) ^ (cl & 7)) << 3)];
            #pragma unroll
            for (int mt = 0; mt < 4; ++mt)
                oacc[mt][nt] = __builtin_amdgcn_mfma_f32_16x16x32_bf16(
                    pfr[mt], vf, oacc[mt][nt], 0, 0, 0);
        }
    }

    size_t ob = (size_t)b * (256 * 256);
    #pragma unroll
    for (int mt = 0; mt < 4; ++mt)
        #pragma unroll
        for (int nt = 0; nt < 8; ++nt) {
            int c  = ch * 128 + nt * 16 + li;
            int i0 = wv * 64 + mt * 16 + 4 * g;
            #pragma unroll
            for (int q2 = 0; q2 < 4; ++q2)
                out[ob + (size_t)(i0 + q2) * 256 + c] = oacc[mt][nt][q2];
        }
}

extern "C" void kernel_launch(void* const* d_in, const int* in_sizes, int n_in,
                              void* d_out, int out_size, void* d_ws, size_t ws_size,
                              hipStream_t stream) {
    (void)in_sizes; (void)n_in; (void)out_size; (void)ws_size;
    const int*   seq   = (const int*)d_in[0];
    const float* emb   = (const float*)d_in[1];
    const float* pos   = (const float*)d_in[2];
    const float* W     = (const float*)d_in[3];
    const float* a1    = (const float*)d_in[4];
    const float* a2    = (const float*)d_in[5];
    const float* gamma = (const float*)d_in[6];
    const float* beta  = (const float*)d_in[7];

    char* ws = (char*)d_ws;
    u16*   wbt = (u16*)ws;                       // 131072 B
    float* w1  = (float*)(ws + 131072);          // 1024 B
    float* w2  = (float*)(ws + 132096);          // 1024 B
    float* s1g = (float*)(ws + 133120);          // 262144 B
    float* s2g = (float*)(ws + 395264);          // 262144 B
    u16*   htg = (u16*)(ws + 657408);            // 33554432 B (16B-aligned)

    hipLaunchKernelGGL(prep, dim3(68), dim3(256), 0, stream, W, a1, a2, wbt, w1, w2);
    hipLaunchKernelGGL(kA, dim3(512), dim3(256), 0, stream,
                       seq, emb, pos, gamma, beta, wbt, w1, w2, s1g, s2g, htg);
    hipLaunchKernelGGL(kB, dim3(512), dim3(256), 0, stream,
                       s1g, s2g, htg, (float*)d_out);
}

// Round 4
// 107.832 us; speedup vs baseline: 1.0454x; 1.0454x over previous
//
#include <hip/hip_runtime.h>
#include <hip/hip_bf16.h>

#define ALPHA  0.2f
#define L2E    1.4426950408889634f

typedef __attribute__((ext_vector_type(8))) short  short8;
typedef __attribute__((ext_vector_type(4))) float  f32x4;
typedef unsigned short u16;

__device__ __forceinline__ u16 f2bf(float f) {
    union { float f; unsigned int u; } v; v.f = f;
    unsigned int r = (v.u + 0x7FFFu + ((v.u >> 16) & 1u)) >> 16;   // RNE
    return (u16)r;
}
__device__ __forceinline__ float lrelu(float x) { return fmaxf(x, ALPHA * x); }

// ---------------- prep: W -> wbt (bf16, [c][k]); w1 = W@a1, w2 = W@a2 ------
__global__ void prep(const float* __restrict__ W, const float* __restrict__ a1,
                     const float* __restrict__ a2, u16* __restrict__ wbt,
                     float* __restrict__ w1, float* __restrict__ w2) {
    int b = blockIdx.x;
    if (b < 64) {
        int t  = threadIdx.x;
        int kk = t >> 6;
        int c4 = (t & 63) * 4;
        int k  = b * 4 + kk;
        float4 w = *(const float4*)(W + (size_t)k * 256 + c4);
        wbt[(c4 + 0) * 256 + k] = f2bf(w.x);
        wbt[(c4 + 1) * 256 + k] = f2bf(w.y);
        wbt[(c4 + 2) * 256 + k] = f2bf(w.z);
        wbt[(c4 + 3) * 256 + k] = f2bf(w.w);
    } else {
        int bb = b - 64;                       // 0..3
        int wv = threadIdx.x >> 6, lane = threadIdx.x & 63;
        for (int kk = 0; kk < 16; ++kk) {
            int k = bb * 64 + wv * 16 + kk;
            float4 wv4 = *(const float4*)(W + (size_t)k * 256 + 4 * lane);
            float4 a14 = *(const float4*)(a1 + 4 * lane);
            float4 a24 = *(const float4*)(a2 + 4 * lane);
            float d1 = wv4.x*a14.x + wv4.y*a14.y + wv4.z*a14.z + wv4.w*a14.w;
            float d2 = wv4.x*a24.x + wv4.y*a24.y + wv4.z*a24.z + wv4.w*a24.w;
            #pragma unroll
            for (int off = 32; off; off >>= 1) {
                d1 += __shfl_xor(d1, off);
                d2 += __shfl_xor(d2, off);
            }
            if (lane == 0) { w1[k] = d1; w2[k] = d2; }
        }
    }
}

// ======================= Kernel A: gather+LN+s1/s2+GEMM1 ====================
// grid 512: block = (b, ihalf). LDS 64KB -> 2 blocks/CU.
// xa tile [128 r][256 k] bf16, 512B rows, 16B slot swizzle: slot = (k>>3)^(r&7)
// then reused as hT tile [256 c][128 i] bf16, 256B rows, slot = (i>>3)^(c&7)
__global__ __launch_bounds__(256, 2)
void kA(const int* __restrict__ item_seq, const float* __restrict__ emb,
        const float* __restrict__ pos, const float* __restrict__ gamma,
        const float* __restrict__ beta, const u16* __restrict__ wbt,
        const float* __restrict__ w1, const float* __restrict__ w2,
        float* __restrict__ s1g, float* __restrict__ s2g, u16* __restrict__ htg)
{
    __shared__ u16 xa[128 * 256];   // 64 KB
    const int bid = blockIdx.x;
    const int b   = bid >> 1, ih = bid & 1;
    const int tid = threadIdx.x;
    const int lane = tid & 63, wv = tid >> 6, g = lane >> 4, li = lane & 15;

    // ---- Phase A: gather + LN + fused s1/s2 dots (wave per row, no spill) --
    {
        float4 g4 = *(const float4*)(gamma + 4 * lane);
        float4 b4 = *(const float4*)(beta  + 4 * lane);
        float4 u4 = *(const float4*)(w1    + 4 * lane);
        float4 t4 = *(const float4*)(w2    + 4 * lane);
        #pragma unroll 4
        for (int it = 0; it < 32; ++it) {
            int rl = wv * 32 + it;              // wave-uniform
            int r  = ih * 128 + rl;
            int iw = item_seq[(size_t)b * 256 + r];   // uniform -> scalar load
            float4 e = *(const float4*)(emb + (size_t)iw * 256 + 4 * lane);
            float4 p = *(const float4*)(pos + (size_t)r  * 256 + 4 * lane);
            float4 v; v.x = e.x + p.x; v.y = e.y + p.y; v.z = e.z + p.z; v.w = e.w + p.w;
            float s = v.x + v.y + v.z + v.w;
            float q = v.x*v.x + v.y*v.y + v.z*v.z + v.w*v.w;
            #pragma unroll
            for (int off = 32; off; off >>= 1) {
                s += __shfl_xor(s, off);
                q += __shfl_xor(q, off);
            }
            float mu  = s * (1.0f / 256.0f);
            float var = q * (1.0f / 256.0f) - mu * mu;
            float rs  = rsqrtf(var + 1e-12f);
            float y0 = (v.x - mu) * rs * g4.x + b4.x;
            float y1 = (v.y - mu) * rs * g4.y + b4.y;
            float y2 = (v.z - mu) * rs * g4.z + b4.z;
            float y3 = (v.w - mu) * rs * g4.w + b4.w;
            float d1 = y0*u4.x + y1*u4.y + y2*u4.z + y3*u4.w;
            float d2 = y0*t4.x + y1*t4.y + y2*t4.z + y3*t4.w;
            #pragma unroll
            for (int off = 32; off; off >>= 1) {
                d1 += __shfl_xor(d1, off);
                d2 += __shfl_xor(d2, off);
            }
            if (lane == 0) { s1g[b * 256 + r] = d1; s2g[b * 256 + r] = d2; }
            ushort4 o; o.x = f2bf(y0); o.y = f2bf(y1); o.z = f2bf(y2); o.w = f2bf(y3);
            *(ushort4*)&xa[rl * 256 + ((((lane >> 1) ^ (rl & 7))) << 3) + (lane & 1) * 4] = o;
        }
    }
    __syncthreads();

    // ---- GEMM1: h[128x256] = xa @ Wb ; B-frags direct from global (L2) ----
    const int im = wv >> 1;    // i 64-range
    const int ng = wv & 1;     // c 128-range
    f32x4 acc[4][8];
    #pragma unroll
    for (int mt = 0; mt < 4; ++mt)
        #pragma unroll
        for (int nt = 0; nt < 8; ++nt)
            acc[mt][nt] = (f32x4){0.f, 0.f, 0.f, 0.f};

    #pragma unroll
    for (int ks = 0; ks < 8; ++ks) {
        short8 bfr[8];
        #pragma unroll
        for (int nt = 0; nt < 8; ++nt) {
            int c = ng * 128 + nt * 16 + li;
            bfr[nt] = *(const short8*)(wbt + (size_t)c * 256 + ks * 32 + g * 8);
        }
        #pragma unroll
        for (int mt = 0; mt < 4; ++mt) {
            int rl = im * 64 + mt * 16 + li;
            int kc = ks * 4 + g;
            short8 af = *(const short8*)&xa[rl * 256 + ((kc ^ (rl & 7)) << 3)];
            #pragma unroll
            for (int nt = 0; nt < 8; ++nt)
                acc[mt][nt] = __builtin_amdgcn_mfma_f32_16x16x32_bf16(
                    af, bfr[nt], acc[mt][nt], 0, 0, 0);
        }
    }
    __syncthreads();   // xa reads done; safe to overwrite with hT

    // ---- transpose: hT tile [c 256][i 128], 256B rows ----------------------
    #pragma unroll
    for (int mt = 0; mt < 4; ++mt)
        #pragma unroll
        for (int nt = 0; nt < 8; ++nt) {
            int c  = ng * 128 + nt * 16 + li;
            int il = im * 64 + mt * 16 + 4 * g;
            uint2 v;
            v.x = (unsigned)f2bf(acc[mt][nt][0]) | ((unsigned)f2bf(acc[mt][nt][1]) << 16);
            v.y = (unsigned)f2bf(acc[mt][nt][2]) | ((unsigned)f2bf(acc[mt][nt][3]) << 16);
            *(uint2*)&xa[c * 128 + (((il >> 3) ^ (c & 7)) << 3) + (il & 7)] = v;
        }
    __syncthreads();

    // ---- coalesced store: thread = c row (256B), pre-swizzled global layout
    {
        const uint4* sp = (const uint4*)&xa[(size_t)tid * 128];
        uint4* dp = (uint4*)(htg + ((size_t)(b * 256 + tid)) * 256 + ih * 128);
        #pragma unroll
        for (int it = 0; it < 16; ++it) dp[it] = sp[it];
    }
}

// ======================= Kernel B: softmax + PV =============================
// grid 512: block = (b, chalf). LDS ~68KB -> 2 blocks/CU.
__global__ __launch_bounds__(256, 2)
void kB(const float* __restrict__ s1g, const float* __restrict__ s2g,
        const u16* __restrict__ htg, float* __restrict__ out)
{
    __shared__ u16   ht[128 * 256];          // 64 KB, [c-local][j-slots] 512B rows
    __shared__ float s2s[256], s1S[256], mS[256], lS[256];
    __shared__ float red[4];
    const int bid = blockIdx.x;
    const int b   = bid >> 1, ch = bid & 1;
    const int tid = threadIdx.x;
    const int lane = tid & 63, wv = tid >> 6, g = lane >> 4, li = lane & 15;

    // stats inputs first (so barrier #1 is cheap)
    float s1v = s1g[b * 256 + tid];
    float s2v = s2g[b * 256 + tid];
    s2s[tid] = s2v; s1S[tid] = s1v;
    float m = s2v;
    #pragma unroll
    for (int off = 32; off; off >>= 1) m = fmaxf(m, __shfl_xor(m, off));
    if (lane == 0) red[wv] = m;
    __syncthreads();

    // issue hT staging (16 x 4KB rounds); latency hides under stats below
    {
        const u16* sb = htg + ((size_t)(b * 256 + ch * 128)) * 256;
        #pragma unroll
        for (int it = 0; it < 16; ++it) {
            const u16* src = sb + it * 2048 + wv * 512 + lane * 8;
            u16* dst = &ht[it * 2048 + wv * 512];
            __builtin_amdgcn_global_load_lds(
                (const __attribute__((address_space(1))) void*)src,
                (__attribute__((address_space(3))) void*)dst, 16, 0, 0);
        }
    }

    // softmax stats: exact row max via separable trick, then denom
    {
        float s2max = fmaxf(fmaxf(red[0], red[1]), fmaxf(red[2], red[3]));
        float mi  = lrelu(s1v + s2max);
        float sum = 0.f;
        #pragma unroll 4
        for (int j = 0; j < 256; ++j) {
            float e = lrelu(s1v + s2s[j]);
            sum += __builtin_amdgcn_exp2f((e - mi) * L2E);
        }
        mS[tid] = mi; lS[tid] = 1.0f / sum;
    }
    __syncthreads();   // drains staging vmcnt + publishes mS/lS

    // ---- PV: out[i 256][c 128] = P @ h ------------------------------------
    f32x4 oacc[4][8];
    #pragma unroll
    for (int mt = 0; mt < 4; ++mt)
        #pragma unroll
        for (int nt = 0; nt < 8; ++nt)
            oacc[mt][nt] = (f32x4){0.f, 0.f, 0.f, 0.f};

    float s1r[4], mv[4], lv[4];
    #pragma unroll
    for (int mt = 0; mt < 4; ++mt) {
        int i = wv * 64 + mt * 16 + li;
        s1r[mt] = s1S[i]; mv[mt] = mS[i]; lv[mt] = lS[i];
    }

    #pragma unroll
    for (int js = 0; js < 8; ++js) {
        float s2l[8];
        #pragma unroll
        for (int jj = 0; jj < 8; ++jj) s2l[jj] = s2s[js * 32 + g * 8 + jj];

        short8 pfr[4];
        #pragma unroll
        for (int mt = 0; mt < 4; ++mt) {
            union { unsigned int u[4]; short8 s; } pk;
            #pragma unroll
            for (int q2 = 0; q2 < 4; ++q2) {
                float e0 = lrelu(s1r[mt] + s2l[2 * q2]);
                float e1 = lrelu(s1r[mt] + s2l[2 * q2 + 1]);
                float p0 = __builtin_amdgcn_exp2f((e0 - mv[mt]) * L2E) * lv[mt];
                float p1 = __builtin_amdgcn_exp2f((e1 - mv[mt]) * L2E) * lv[mt];
                pk.u[q2] = (unsigned int)f2bf(p0) | ((unsigned int)f2bf(p1) << 16);
            }
            pfr[mt] = pk.s;
        }
        #pragma unroll
        for (int nt = 0; nt < 8; ++nt) {
            int cl = nt * 16 + li;
            short8 vf = *(const short8*)&ht[cl * 256 + (((js * 4 + g) ^ (cl & 7)) << 3)];
            #pragma unroll
            for (int mt = 0; mt < 4; ++mt)
                oacc[mt][nt] = __builtin_amdgcn_mfma_f32_16x16x32_bf16(
                    pfr[mt], vf, oacc[mt][nt], 0, 0, 0);
        }
    }

    size_t ob = (size_t)b * (256 * 256);
    #pragma unroll
    for (int mt = 0; mt < 4; ++mt)
        #pragma unroll
        for (int nt = 0; nt < 8; ++nt) {
            int c  = ch * 128 + nt * 16 + li;
            int i0 = wv * 64 + mt * 16 + 4 * g;
            #pragma unroll
            for (int q2 = 0; q2 < 4; ++q2)
                out[ob + (size_t)(i0 + q2) * 256 + c] = oacc[mt][nt][q2];
        }
}

extern "C" void kernel_launch(void* const* d_in, const int* in_sizes, int n_in,
                              void* d_out, int out_size, void* d_ws, size_t ws_size,
                              hipStream_t stream) {
    (void)in_sizes; (void)n_in; (void)out_size; (void)ws_size;
    const int*   seq   = (const int*)d_in[0];
    const float* emb   = (const float*)d_in[1];
    const float* pos   = (const float*)d_in[2];
    const float* W     = (const float*)d_in[3];
    const float* a1    = (const float*)d_in[4];
    const float* a2    = (const float*)d_in[5];
    const float* gamma = (const float*)d_in[6];
    const float* beta  = (const float*)d_in[7];

    char* ws = (char*)d_ws;
    u16*   wbt = (u16*)ws;                       // 131072 B
    float* w1  = (float*)(ws + 131072);          // 1024 B
    float* w2  = (float*)(ws + 132096);          // 1024 B
    float* s1g = (float*)(ws + 133120);          // 262144 B
    float* s2g = (float*)(ws + 395264);          // 262144 B
    u16*   htg = (u16*)(ws + 657408);            // 33554432 B (16B-aligned)

    hipLaunchKernelGGL(prep, dim3(68), dim3(256), 0, stream, W, a1, a2, wbt, w1, w2);
    hipLaunchKernelGGL(kA, dim3(512), dim3(256), 0, stream,
                       seq, emb, pos, gamma, beta, wbt, w1, w2, s1g, s2g, htg);
    hipLaunchKernelGGL(kB, dim3(512), dim3(256), 0, stream,
                       s1g, s2g, htg, (float*)d_out);
}

// Round 5
// 100.387 us; speedup vs baseline: 1.1229x; 1.0742x over previous
//
#include <hip/hip_runtime.h>
#include <hip/hip_bf16.h>

#define ALPHA  0.2f
#define L2E    1.4426950408889634f

typedef __attribute__((ext_vector_type(8))) short  short8;
typedef __attribute__((ext_vector_type(4))) float  f32x4;
typedef unsigned short u16;

__device__ __forceinline__ u16 f2bf(float f) {
    union { float f; unsigned int u; } v; v.f = f;
    unsigned int r = (v.u + 0x7FFFu + ((v.u >> 16) & 1u)) >> 16;   // RNE
    return (u16)r;
}
__device__ __forceinline__ float lrelu(float x) { return fmaxf(x, ALPHA * x); }

// ---------------- prep: W -> wbt (bf16, [c][k]); w1 = W@a1, w2 = W@a2 ------
__global__ void prep(const float* __restrict__ W, const float* __restrict__ a1,
                     const float* __restrict__ a2, u16* __restrict__ wbt,
                     float* __restrict__ w1, float* __restrict__ w2) {
    int b = blockIdx.x;
    if (b < 64) {
        int t  = threadIdx.x;
        int kk = t >> 6;
        int c4 = (t & 63) * 4;
        int k  = b * 4 + kk;
        float4 w = *(const float4*)(W + (size_t)k * 256 + c4);
        wbt[(c4 + 0) * 256 + k] = f2bf(w.x);
        wbt[(c4 + 1) * 256 + k] = f2bf(w.y);
        wbt[(c4 + 2) * 256 + k] = f2bf(w.z);
        wbt[(c4 + 3) * 256 + k] = f2bf(w.w);
    } else {
        int bb = b - 64;                       // 0..3
        int wv = threadIdx.x >> 6, lane = threadIdx.x & 63;
        for (int kk = 0; kk < 16; ++kk) {
            int k = bb * 64 + wv * 16 + kk;
            float4 wv4 = *(const float4*)(W + (size_t)k * 256 + 4 * lane);
            float4 a14 = *(const float4*)(a1 + 4 * lane);
            float4 a24 = *(const float4*)(a2 + 4 * lane);
            float d1 = wv4.x*a14.x + wv4.y*a14.y + wv4.z*a14.z + wv4.w*a14.w;
            float d2 = wv4.x*a24.x + wv4.y*a24.y + wv4.z*a24.z + wv4.w*a24.w;
            #pragma unroll
            for (int off = 32; off; off >>= 1) {
                d1 += __shfl_xor(d1, off);
                d2 += __shfl_xor(d2, off);
            }
            if (lane == 0) { w1[k] = d1; w2[k] = d2; }
        }
    }
}

// ---------------- prep2: gw1 = gamma*w1, gw2 = gamma*w2, scal = {sgw1,sgw2,bw1,bw2}
__global__ void prep2(const float* __restrict__ gamma, const float* __restrict__ beta,
                      const float* __restrict__ w1, const float* __restrict__ w2,
                      float* __restrict__ gw1, float* __restrict__ gw2,
                      float* __restrict__ scal) {
    int t = threadIdx.x;                        // 256 threads
    float w1v = w1[t], w2v = w2[t], g = gamma[t], bt = beta[t];
    float v0 = g * w1v, v1 = g * w2v;
    gw1[t] = v0; gw2[t] = v1;
    float v2 = bt * w1v, v3 = bt * w2v;
    #pragma unroll
    for (int off = 32; off; off >>= 1) {
        v0 += __shfl_xor(v0, off); v1 += __shfl_xor(v1, off);
        v2 += __shfl_xor(v2, off); v3 += __shfl_xor(v3, off);
    }
    __shared__ float red[4][4];
    int wv = t >> 6, lane = t & 63;
    if (lane == 0) { red[wv][0] = v0; red[wv][1] = v1; red[wv][2] = v2; red[wv][3] = v3; }
    __syncthreads();
    if (t == 0) {
        scal[0] = red[0][0] + red[1][0] + red[2][0] + red[3][0];
        scal[1] = red[0][1] + red[1][1] + red[2][1] + red[3][1];
        scal[2] = red[0][2] + red[1][2] + red[2][2] + red[3][2];
        scal[3] = red[0][3] + red[1][3] + red[2][3] + red[3][3];
    }
}

// ======================= Kernel A: gather+LN+s1/s2+GEMM1 ====================
// grid 512: block = (b, ihalf). LDS 64KB -> 2 blocks/CU.
// xa as x-tile: [128 r][256 k] bf16, 512B rows, slot swizzle (k>>3)^(r&7)
// xa as hT-tile: [256 c][128 i] bf16, 256B rows, slot swizzle (i>>3)^(c&7)
// htg layout: [b][ih][c 256][il-slots 128] -> each block writes 64KB contiguous
__global__ __launch_bounds__(256, 2)
void kA(const int* __restrict__ item_seq, const float* __restrict__ emb,
        const float* __restrict__ pos, const float* __restrict__ gamma,
        const float* __restrict__ beta, const u16* __restrict__ wbt,
        const float* __restrict__ gw1, const float* __restrict__ gw2,
        const float* __restrict__ scal,
        float* __restrict__ s1g, float* __restrict__ s2g, u16* __restrict__ htg)
{
    __shared__ u16 xa[128 * 256];   // 64 KB
    const int bid = blockIdx.x;
    const int b   = bid >> 1, ih = bid & 1;
    const int tid = threadIdx.x;
    const int lane = tid & 63, wv = tid >> 6, g = lane >> 4, li = lane & 15;

    // ---- Phase A: gather + LN; s1/s2 via raw-v dots, ONE shfl chain --------
    {
        float4 g4 = *(const float4*)(gamma + 4 * lane);
        float4 b4 = *(const float4*)(beta  + 4 * lane);
        float4 u4 = *(const float4*)(gw1   + 4 * lane);
        float4 t4 = *(const float4*)(gw2   + 4 * lane);
        float4 sc = *(const float4*)scal;       // sgw1, sgw2, bw1, bw2
        #pragma unroll 4
        for (int it = 0; it < 32; ++it) {
            int rl = wv * 32 + it;              // wave-uniform
            int r  = ih * 128 + rl;
            int iw = item_seq[(size_t)b * 256 + r];   // uniform -> scalar load
            float4 e = *(const float4*)(emb + (size_t)iw * 256 + 4 * lane);
            float4 p = *(const float4*)(pos + (size_t)r  * 256 + 4 * lane);
            float4 v; v.x = e.x + p.x; v.y = e.y + p.y; v.z = e.z + p.z; v.w = e.w + p.w;
            float s = v.x + v.y + v.z + v.w;
            float q = v.x*v.x + v.y*v.y + v.z*v.z + v.w*v.w;
            float d1 = v.x*u4.x + v.y*u4.y + v.z*u4.z + v.w*u4.w;
            float d2 = v.x*t4.x + v.y*t4.y + v.z*t4.z + v.w*t4.w;
            #pragma unroll
            for (int off = 32; off; off >>= 1) {   // one chain, ILP-4
                s  += __shfl_xor(s,  off);
                q  += __shfl_xor(q,  off);
                d1 += __shfl_xor(d1, off);
                d2 += __shfl_xor(d2, off);
            }
            float mu  = s * (1.0f / 256.0f);
            float var = q * (1.0f / 256.0f) - mu * mu;
            float rs  = rsqrtf(var + 1e-12f);
            if (lane == 0) {
                s1g[b * 256 + r] = rs * (d1 - mu * sc.x) + sc.z;
                s2g[b * 256 + r] = rs * (d2 - mu * sc.y) + sc.w;
            }
            float y0 = (v.x - mu) * rs * g4.x + b4.x;
            float y1 = (v.y - mu) * rs * g4.y + b4.y;
            float y2 = (v.z - mu) * rs * g4.z + b4.z;
            float y3 = (v.w - mu) * rs * g4.w + b4.w;
            ushort4 o; o.x = f2bf(y0); o.y = f2bf(y1); o.z = f2bf(y2); o.w = f2bf(y3);
            *(ushort4*)&xa[rl * 256 + ((((lane >> 1) ^ (rl & 7))) << 3) + (lane & 1) * 4] = o;
        }
    }
    __syncthreads();

    // ---- GEMM1: h[128x256] = xa @ Wb, two n-half passes (acc 64 regs) ------
    const int im = wv >> 1;    // i 64-range
    const int ng = wv & 1;     // c 64-range within half
    unsigned int stash[32];    // half-0 results, packed bf16
    f32x4 acc[4][4];

    for (int half = 0; half < 2; ++half) {
        #pragma unroll
        for (int mt = 0; mt < 4; ++mt)
            #pragma unroll
            for (int nt = 0; nt < 4; ++nt)
                acc[mt][nt] = (f32x4){0.f, 0.f, 0.f, 0.f};

        #pragma unroll
        for (int ks = 0; ks < 8; ++ks) {
            short8 bfr[4];
            #pragma unroll
            for (int nt = 0; nt < 4; ++nt) {
                int c = half * 128 + ng * 64 + nt * 16 + li;
                bfr[nt] = *(const short8*)(wbt + (size_t)c * 256 + ks * 32 + g * 8);
            }
            #pragma unroll
            for (int mt = 0; mt < 4; ++mt) {
                int rl = im * 64 + mt * 16 + li;
                int kc = ks * 4 + g;
                short8 af = *(const short8*)&xa[rl * 256 + ((kc ^ (rl & 7)) << 3)];
                #pragma unroll
                for (int nt = 0; nt < 4; ++nt)
                    acc[mt][nt] = __builtin_amdgcn_mfma_f32_16x16x32_bf16(
                        af, bfr[nt], acc[mt][nt], 0, 0, 0);
            }
        }
        if (half == 0) {
            #pragma unroll
            for (int mt = 0; mt < 4; ++mt)
                #pragma unroll
                for (int nt = 0; nt < 4; ++nt) {
                    int t = (mt * 4 + nt) * 2;
                    stash[t]   = (unsigned)f2bf(acc[mt][nt][0]) | ((unsigned)f2bf(acc[mt][nt][1]) << 16);
                    stash[t+1] = (unsigned)f2bf(acc[mt][nt][2]) | ((unsigned)f2bf(acc[mt][nt][3]) << 16);
                }
        }
    }
    __syncthreads();   // xa reads done; safe to overwrite with hT

    // ---- transpose: hT tile [c 256][i-local 128], 256B rows ----------------
    #pragma unroll
    for (int half = 0; half < 2; ++half)
        #pragma unroll
        for (int mt = 0; mt < 4; ++mt)
            #pragma unroll
            for (int nt = 0; nt < 4; ++nt) {
                int c  = half * 128 + ng * 64 + nt * 16 + li;
                int il = im * 64 + mt * 16 + 4 * g;
                unsigned int lo, hi;
                if (half == 0) {
                    int t = (mt * 4 + nt) * 2;
                    lo = stash[t]; hi = stash[t + 1];
                } else {
                    lo = (unsigned)f2bf(acc[mt][nt][0]) | ((unsigned)f2bf(acc[mt][nt][1]) << 16);
                    hi = (unsigned)f2bf(acc[mt][nt][2]) | ((unsigned)f2bf(acc[mt][nt][3]) << 16);
                }
                uint2 v; v.x = lo; v.y = hi;
                *(uint2*)&xa[c * 128 + (((il >> 3) ^ (c & 7)) << 3) + (il & 7)] = v;
            }
    __syncthreads();

    // ---- store: block-contiguous 64KB, lane-adjacent 16B (fully coalesced) -
    {
        const uint4* sp = (const uint4*)xa;
        uint4* dp = (uint4*)(htg + (size_t)(b * 2 + ih) * 32768);
        #pragma unroll
        for (int it = 0; it < 16; ++it) dp[it * 256 + tid] = sp[it * 256 + tid];
    }
}

// ======================= Kernel B: softmax + PV =============================
// grid 512: block = (b, chalf). LDS ~68KB -> 2 blocks/CU.
// ht image: [ih][cl 128][il-slots 128] (swizzle already baked into htg)
__global__ __launch_bounds__(256, 2)
void kB(const float* __restrict__ s1g, const float* __restrict__ s2g,
        const u16* __restrict__ htg, float* __restrict__ out)
{
    __shared__ u16   ht[2 * 128 * 128];      // 64 KB
    __shared__ float s2s[256], s1S[256], mS[256], lS[256];
    __shared__ float red[4];
    const int bid = blockIdx.x;
    const int b   = bid >> 1, ch = bid & 1;
    const int tid = threadIdx.x;
    const int lane = tid & 63, wv = tid >> 6, g = lane >> 4, li = lane & 15;

    // stats inputs first (so barrier #1 is cheap)
    float s1v = s1g[b * 256 + tid];
    float s2v = s2g[b * 256 + tid];
    s2s[tid] = s2v; s1S[tid] = s1v;
    float m = s2v;
    #pragma unroll
    for (int off = 32; off; off >>= 1) m = fmaxf(m, __shfl_xor(m, off));
    if (lane == 0) red[wv] = m;
    __syncthreads();

    // issue hT staging (two 32KB linear chunks); latency hides under stats
    {
        #pragma unroll
        for (int ihh = 0; ihh < 2; ++ihh)
            #pragma unroll
            for (int it = 0; it < 8; ++it) {
                const u16* src = htg + (size_t)(b * 2 + ihh) * 32768 + ch * 16384
                                 + it * 2048 + wv * 512 + lane * 8;
                u16* dst = &ht[ihh * 16384 + it * 2048 + wv * 512];
                __builtin_amdgcn_global_load_lds(
                    (const __attribute__((address_space(1))) void*)src,
                    (__attribute__((address_space(3))) void*)dst, 16, 0, 0);
            }
    }

    // softmax stats: exact row max via separable trick, then denom (vectorized)
    {
        float s2max = fmaxf(fmaxf(red[0], red[1]), fmaxf(red[2], red[3]));
        float mi  = lrelu(s1v + s2max);
        float sum = 0.f;
        const float4* s2v4 = (const float4*)s2s;
        #pragma unroll 8
        for (int j4 = 0; j4 < 64; ++j4) {
            float4 sv = s2v4[j4];
            sum += __builtin_amdgcn_exp2f((lrelu(s1v + sv.x) - mi) * L2E);
            sum += __builtin_amdgcn_exp2f((lrelu(s1v + sv.y) - mi) * L2E);
            sum += __builtin_amdgcn_exp2f((lrelu(s1v + sv.z) - mi) * L2E);
            sum += __builtin_amdgcn_exp2f((lrelu(s1v + sv.w) - mi) * L2E);
        }
        mS[tid] = mi; lS[tid] = 1.0f / sum;
    }
    __syncthreads();   // drains staging vmcnt + publishes mS/lS

    // ---- PV: out[i 256][c 128] = P @ h ------------------------------------
    f32x4 oacc[4][8];
    #pragma unroll
    for (int mt = 0; mt < 4; ++mt)
        #pragma unroll
        for (int nt = 0; nt < 8; ++nt)
            oacc[mt][nt] = (f32x4){0.f, 0.f, 0.f, 0.f};

    float s1r[4], mv[4], lv[4];
    #pragma unroll
    for (int mt = 0; mt < 4; ++mt) {
        int i = wv * 64 + mt * 16 + li;
        s1r[mt] = s1S[i]; mv[mt] = mS[i]; lv[mt] = lS[i];
    }

    #pragma unroll
    for (int js = 0; js < 8; ++js) {
        float s2l[8];
        #pragma unroll
        for (int jj = 0; jj < 8; ++jj) s2l[jj] = s2s[js * 32 + g * 8 + jj];

        short8 pfr[4];
        #pragma unroll
        for (int mt = 0; mt < 4; ++mt) {
            union { unsigned int u[4]; short8 s; } pk;
            #pragma unroll
            for (int q2 = 0; q2 < 4; ++q2) {
                float e0 = lrelu(s1r[mt] + s2l[2 * q2]);
                float e1 = lrelu(s1r[mt] + s2l[2 * q2 + 1]);
                float p0 = __builtin_amdgcn_exp2f((e0 - mv[mt]) * L2E) * lv[mt];
                float p1 = __builtin_amdgcn_exp2f((e1 - mv[mt]) * L2E) * lv[mt];
                pk.u[q2] = (unsigned int)f2bf(p0) | ((unsigned int)f2bf(p1) << 16);
            }
            pfr[mt] = pk.s;
        }
        int jb0 = js * 4 + g;            // j-block 0..31
        int ihh = jb0 >> 4, jbl = jb0 & 15;
        #pragma unroll
        for (int nt = 0; nt < 8; ++nt) {
            int cl = nt * 16 + li;
            short8 vf = *(const short8*)&ht[ihh * 16384 + cl * 128 + ((jbl ^ (cl & 7)) << 3)];
            #pragma unroll
            for (int mt = 0; mt < 4; ++mt)
                oacc[mt][nt] = __builtin_amdgcn_mfma_f32_16x16x32_bf16(
                    pfr[mt], vf, oacc[mt][nt], 0, 0, 0);
        }
    }

    size_t ob = (size_t)b * (256 * 256);
    #pragma unroll
    for (int mt = 0; mt < 4; ++mt)
        #pragma unroll
        for (int nt = 0; nt < 8; ++nt) {
            int c  = ch * 128 + nt * 16 + li;
            int i0 = wv * 64 + mt * 16 + 4 * g;
            #pragma unroll
            for (int q2 = 0; q2 < 4; ++q2)
                out[ob + (size_t)(i0 + q2) * 256 + c] = oacc[mt][nt][q2];
        }
}

extern "C" void kernel_launch(void* const* d_in, const int* in_sizes, int n_in,
                              void* d_out, int out_size, void* d_ws, size_t ws_size,
                              hipStream_t stream) {
    (void)in_sizes; (void)n_in; (void)out_size; (void)ws_size;
    const int*   seq   = (const int*)d_in[0];
    const float* emb   = (const float*)d_in[1];
    const float* pos   = (const float*)d_in[2];
    const float* W     = (const float*)d_in[3];
    const float* a1    = (const float*)d_in[4];
    const float* a2    = (const float*)d_in[5];
    const float* gamma = (const float*)d_in[6];
    const float* beta  = (const float*)d_in[7];

    char* ws = (char*)d_ws;
    u16*   wbt  = (u16*)ws;                      // 131072 B
    float* w1   = (float*)(ws + 131072);         // 1 KB
    float* w2   = (float*)(ws + 132096);         // 1 KB
    float* gw1f = (float*)(ws + 133120);         // 1 KB
    float* gw2f = (float*)(ws + 134144);         // 1 KB
    float* scal = (float*)(ws + 135168);         // 16 B (padded to 1 KB)
    float* s1g  = (float*)(ws + 136192);         // 256 KB
    float* s2g  = (float*)(ws + 398336);         // 256 KB
    u16*   htg  = (u16*)(ws + 660480);           // 32 MB, 16B-aligned

    hipLaunchKernelGGL(prep,  dim3(68), dim3(256), 0, stream, W, a1, a2, wbt, w1, w2);
    hipLaunchKernelGGL(prep2, dim3(1),  dim3(256), 0, stream, gamma, beta, w1, w2, gw1f, gw2f, scal);
    hipLaunchKernelGGL(kA, dim3(512), dim3(256), 0, stream,
                       seq, emb, pos, gamma, beta, wbt, gw1f, gw2f, scal, s1g, s2g, htg);
    hipLaunchKernelGGL(kB, dim3(512), dim3(256), 0, stream,
                       s1g, s2g, htg, (float*)d_out);
}